// Round 11
// baseline (294.141 us; speedup 1.0000x reference)
//
#include <hip/hip_runtime.h>

#define DIMV 1024
#define SSZ 512
#define MSZ 4096
#define LSZ 8192
#define KPROM 128
#define NCAND 16384
#define NPAIR 528  // 128x128 tiles over lower triangle incl diagonal: 32*33/2

typedef __attribute__((ext_vector_type(4))) float f32x4;
typedef __attribute__((ext_vector_type(4))) unsigned int u32x4;
typedef __attribute__((ext_vector_type(4))) unsigned short u16x4;
typedef __attribute__((ext_vector_type(8))) __bf16 bf16x8;

// ---------------- output layout (float element offsets) ----------------
#define OUT_S 0ull
#define OUT_M 524288ull
#define OUT_L 4718592ull
#define OUT_MU 13107200ull
#define OUT_LU 13111296ull
#define OUT_SPTR 13119488ull

// ---- scratch inside out_l region (8,388,608 floats; erased last by kI) ----
#define SC_BF16 0ull          // 4096x1024 bf16 (2,097,152 float slots)
#define SC_NORMS 2100000ull   // 16384
#define SC_TOPIDX 2117000ull  // 128 ints
#define SC_LPART 2120000ull   // 128*1024
#define SC_RV 2260000ull      // 1024 (zeroed by kA block 0)
#define SC_LMEAN 2262000ull   // 1024
#define SC_BPK 2414000ull     // u64 packed argmax (even offset -> 8B aligned; zeroed by kA)
#define SC_MNORM 2415000ull   // 4096
#define SC_SIMS 2420000ull    // 4096
#define SC_PPV 2425000ull     // 528 partial max vals
#define SC_PPI 2427000ull     // 528 partial max flat idx

__device__ __forceinline__ float wave_sum(float v) {
#pragma unroll
  for (int o = 32; o > 0; o >>= 1) v += __shfl_down(v, o, 64);
  return v;
}
__device__ __forceinline__ void wave_maxidx(float& v, int& i) {
#pragma unroll
  for (int o = 32; o > 0; o >>= 1) {
    float ov = __shfl_down(v, o, 64);
    int oi = __shfl_down(i, o, 64);
    if (ov > v || (ov == v && oi < i)) { v = ov; i = oi; }
  }
}
__device__ __forceinline__ void wave_minidx(float& v, int& i) {
#pragma unroll
  for (int o = 32; o > 0; o >>= 1) {
    float ov = __shfl_down(v, o, 64);
    int oi = __shfl_down(i, o, 64);
    if (ov < v || (ov == v && oi < i)) { v = ov; i = oi; }
  }
}
__device__ __forceinline__ unsigned short f2bf(float x) {  // RNE float->bf16
  unsigned u = __float_as_uint(x);
  return (unsigned short)((u + 0x7FFFu + ((u >> 16) & 1u)) >> 16);
}
// async global->LDS, 16B per lane; LDS dest = wave-uniform base + lane*16
__device__ __forceinline__ void gload16(const unsigned short* g, unsigned short* l) {
  __builtin_amdgcn_global_load_lds((const __attribute__((address_space(1))) unsigned int*)(g),
                                   (__attribute__((address_space(3))) unsigned int*)(l), 16, 0, 0);
}

// ============ kA: l-part (128 blk) + cand norms (1024 blk, 16 rows)
// ============     + bf16 M + mnorm (256 blk, 16 rows). Block 0 zeroes rv + bestPack.
__global__ void kA(const float* __restrict__ cand, const float* __restrict__ l_memory,
                   const float* __restrict__ m, float* __restrict__ norms,
                   float* __restrict__ lpart, unsigned short* __restrict__ mb,
                   float* __restrict__ mnorm, float* __restrict__ rv,
                   unsigned long long* __restrict__ bestPack) {
  int b = blockIdx.x, t = threadIdx.x, lane = t & 63, w = t >> 6;
  if (b < 128) {  // l column partial sums, 64 rows/block, 4 independent accumulators
    if (b == 0) {  // zero rv + bestPack for kBC/kD (kA precedes them: stream order)
      f32x4 z = {0.f, 0.f, 0.f, 0.f};
      ((f32x4*)rv)[t] = z;
      if (t == 0) bestPack[0] = 0ull;
    }
    f32x4 a0 = {0.f, 0.f, 0.f, 0.f}, a1 = a0, a2 = a0, a3 = a0;
    const f32x4* base = (const f32x4*)(l_memory + (size_t)b * 64 * DIMV);
#pragma unroll 4
    for (int r = 0; r < 64; r += 4) {
      a0 += base[(r + 0) * 256 + t];
      a1 += base[(r + 1) * 256 + t];
      a2 += base[(r + 2) * 256 + t];
      a3 += base[(r + 3) * 256 + t];
    }
    f32x4 a = (a0 + a1) + (a2 + a3);
    ((f32x4*)(lpart + (size_t)b * DIMV))[t] = a;
  } else if (b < 1152) {  // candidate row norms, 16 rows/block (4 rows/wave)
    int r0 = (b - 128) * 16 + w * 4;
    const f32x4* base4 = (const f32x4*)(cand + (size_t)r0 * DIMV);
    float s0 = 0.f, s1 = 0.f, s2 = 0.f, s3 = 0.f;
#pragma unroll
    for (int k = 0; k < 16; ++k) {
      f32x4 v = base4[k * 64 + lane];
      float d = v.x * v.x + v.y * v.y + v.z * v.z + v.w * v.w;
      if (k < 4) s0 += d;
      else if (k < 8) s1 += d;
      else if (k < 12) s2 += d;
      else s3 += d;
    }
    f32x4 sv = {s0, s1, s2, s3};
#pragma unroll
    for (int o = 32; o > 0; o >>= 1) {
      sv.x += __shfl_down(sv.x, o, 64);
      sv.y += __shfl_down(sv.y, o, 64);
      sv.z += __shfl_down(sv.z, o, 64);
      sv.w += __shfl_down(sv.w, o, 64);
    }
    if (lane == 0) {
      f32x4 o4 = {sqrtf(sv.x), sqrtf(sv.y), sqrtf(sv.z), sqrtf(sv.w)};
      *((f32x4*)(norms + r0)) = o4;
    }
  } else {  // m -> bf16 + row norms, 16 rows/block (4 rows/wave)
    int r0 = (b - 1152) * 16 + w * 4;
    const f32x4* base4 = (const f32x4*)(m + (size_t)r0 * DIMV);
    u16x4* mb4 = (u16x4*)(mb + (size_t)r0 * DIMV);
    float s0 = 0.f, s1 = 0.f, s2 = 0.f, s3 = 0.f;
#pragma unroll
    for (int k = 0; k < 16; ++k) {
      int i = k * 64 + lane;
      f32x4 v = base4[i];
      float d = v.x * v.x + v.y * v.y + v.z * v.z + v.w * v.w;
      if (k < 4) s0 += d;
      else if (k < 8) s1 += d;
      else if (k < 12) s2 += d;
      else s3 += d;
      u16x4 h;
      h.x = f2bf(v.x); h.y = f2bf(v.y); h.z = f2bf(v.z); h.w = f2bf(v.w);
      mb4[i] = h;
    }
    f32x4 sv = {s0, s1, s2, s3};
#pragma unroll
    for (int o = 32; o > 0; o >>= 1) {
      sv.x += __shfl_down(sv.x, o, 64);
      sv.y += __shfl_down(sv.y, o, 64);
      sv.z += __shfl_down(sv.z, o, 64);
      sv.w += __shfl_down(sv.w, o, 64);
    }
    if (lane == 0) {
      f32x4 o4 = {sqrtf(sv.x), sqrtf(sv.y), sqrtf(sv.z), sqrtf(sv.w)};
      *((f32x4*)(mnorm + r0)) = o4;
    }
  }
}

// ============ kTG: 530 blocks x 1024 threads ============
//  b==0: exact stable top-128 (8-bit radix, per-wave histograms) — serial, 1 CU
//  b==1: lmean final reduce
//  b>=2: pairmax 128x128 MFMA tiles (threads 0-255; waves 4-15 retire at entry —
//        CDNA s_barrier is satisfied by live waves, exited waves are deallocated)
// The serial top-k hides under 528 MFMA blocks instead of idling 255 CUs.
// LDS overlaid: topk uses 21.6 KB, pair uses 32.8 KB of one shared pool.
__device__ int scan_excl_1024(int v, int* sh, int* total) {
  int t = threadIdx.x;
  sh[t] = v;
  __syncthreads();
  for (int o = 1; o < 1024; o <<= 1) {
    int x = (t >= o) ? sh[t - o] : 0;
    __syncthreads();
    sh[t] += x;
    __syncthreads();
  }
  int incl = sh[t];
  *total = sh[1023];
  __syncthreads();
  return incl - v;
}

__global__ __launch_bounds__(1024) void kTG(
    const float* __restrict__ norms, int* __restrict__ topidx,
    const float* __restrict__ lpart, float* __restrict__ lmean,
    const unsigned short* __restrict__ mb, const float* __restrict__ mnorm,
    float* __restrict__ pv, int* __restrict__ pidx) {
  __shared__ __align__(16) char smem[33024];  // overlay pool
  __shared__ int s_digit, s_sub;
  __shared__ float spv[4];
  __shared__ int spi[4];
  int b = blockIdx.x, t = threadIdx.x;

  if (b == 1) {  // lmean: reduce 128 partials per column, 4 indep accumulators
    float s0 = 0.f, s1 = 0.f, s2 = 0.f, s3 = 0.f;
    for (int p = 0; p < 128; p += 4) {
      s0 += lpart[(size_t)(p + 0) * DIMV + t];
      s1 += lpart[(size_t)(p + 1) * DIMV + t];
      s2 += lpart[(size_t)(p + 2) * DIMV + t];
      s3 += lpart[(size_t)(p + 3) * DIMV + t];
    }
    lmean[t] = ((s0 + s1) + (s2 + s3)) * (1.f / 8192.f);
    return;
  }

  if (b >= 2) {  // ---------------- pairmax tile ----------------
    if (t >= 256) return;  // wave-uniform retire of waves 4..15
    unsigned short* Ash = (unsigned short*)smem;            // 16 KB
    unsigned short* Bsh = (unsigned short*)(smem + 16384);  // 16 KB
    int lane = t & 63, w = t >> 6;
    int tb = b - 2;
    // XCD-contiguous tile order (bijective: 528 = 8*66), then lower-tri decode
    int bs = (tb & 7) * 66 + (tb >> 3);
    int bi = (int)((sqrtf(8.f * (float)bs + 1.f) - 1.f) * 0.5f);
    while (bi * (bi + 1) / 2 > bs) --bi;
    while ((bi + 1) * (bi + 2) / 2 <= bs) ++bi;
    int bj = bs - bi * (bi + 1) / 2;
    int rowA0 = bi * 128, rowB0 = bj * 128;

    int wr = w >> 1, wc = w & 1;          // wave -> 64x64 quadrant
    int rl = lane & 15, kq4 = lane >> 4;  // fragment row/col + k-group
    int swz = rl & 7;                     // read-side XOR key
    int subrow = lane >> 3, gg = lane & 7;
    int gsw = (gg ^ subrow) << 3;  // source-side XOR'd chunk, in shorts

    f32x4 acc[4][4];
    f32x4 z = {0.f, 0.f, 0.f, 0.f};
#pragma unroll
    for (int ti = 0; ti < 4; ++ti)
#pragma unroll
      for (int tj = 0; tj < 4; ++tj) acc[ti][tj] = z;

    for (int kc = 0; kc < DIMV; kc += 64) {
#pragma unroll
      for (int jj = 0; jj < 4; ++jj) {
        int rsub = w * 32 + jj * 8 + subrow;
        gload16(mb + (size_t)(rowA0 + rsub) * DIMV + kc + gsw, Ash + (w * 4 + jj) * 512);
        gload16(mb + (size_t)(rowB0 + rsub) * DIMV + kc + gsw, Bsh + (w * 4 + jj) * 512);
      }
      __syncthreads();
#pragma unroll
      for (int ks = 0; ks < 2; ++ks) {
        int co = (((ks * 4 + kq4) ^ swz) << 3);
        bf16x8 af[4], bfv[4];
#pragma unroll
        for (int ti = 0; ti < 4; ++ti)
          af[ti] = *(const bf16x8*)(Ash + (wr * 64 + ti * 16 + rl) * 64 + co);
#pragma unroll
        for (int tj = 0; tj < 4; ++tj)
          bfv[tj] = *(const bf16x8*)(Bsh + (wc * 64 + tj * 16 + rl) * 64 + co);
#pragma unroll
        for (int ti = 0; ti < 4; ++ti)
#pragma unroll
          for (int tj = 0; tj < 4; ++tj)
            acc[ti][tj] =
                __builtin_amdgcn_mfma_f32_16x16x32_bf16(af[ti], bfv[tj], acc[ti][tj], 0, 0, 0);
      }
      __syncthreads();
    }

    float ni[16], nj4[4];
#pragma unroll
    for (int ti = 0; ti < 4; ++ti)
#pragma unroll
      for (int r = 0; r < 4; ++r)
        ni[ti * 4 + r] = fmaxf(mnorm[rowA0 + wr * 64 + ti * 16 + kq4 * 4 + r], 1e-12f);
#pragma unroll
    for (int tj = 0; tj < 4; ++tj)
      nj4[tj] = fmaxf(mnorm[rowB0 + wc * 64 + tj * 16 + rl], 1e-12f);

    float bv = -3.402823466e38f;
    int bidx = 0x7FFFFFFF;
#pragma unroll
    for (int ti = 0; ti < 4; ++ti)
#pragma unroll
      for (int tj = 0; tj < 4; ++tj)
#pragma unroll
        for (int r = 0; r < 4; ++r) {
          int gi = rowA0 + wr * 64 + ti * 16 + kq4 * 4 + r;
          int gj = rowB0 + wc * 64 + tj * 16 + rl;
          if (gi > gj) {
            float s = acc[ti][tj][r] / (ni[ti * 4 + r] * nj4[tj]);
            int fi = gi * MSZ + gj;
            if (s > bv || (s == bv && fi < bidx)) { bv = s; bidx = fi; }
          }
        }
    wave_maxidx(bv, bidx);
    if (lane == 0) { spv[w] = bv; spi[w] = bidx; }
    __syncthreads();
    if (t == 0) {
      float a = spv[0]; int ai = spi[0];
      for (int i = 1; i < 4; ++i)
        if (spv[i] > a || (spv[i] == a && spi[i] < ai)) { a = spv[i]; ai = spi[i]; }
      pv[tb] = a;
      pidx[tb] = ai;
    }
    return;
  }

  // ---------------- b == 0: top-128 (1024 threads, unchanged algorithm) ----------------
  int* sh = (int*)smem;                                      // 4 KB
  int* histW = (int*)(smem + 4096);                          // [16][257] = 16448 B
  unsigned* s_selkey = (unsigned*)(smem + 4096 + 16448);     // 512 B
  int* s_selidx = (int*)(smem + 4096 + 16448 + 512);         // 512 B
  int w = t >> 6;
  unsigned key[16];
#pragma unroll
  for (int j = 0; j < 16; ++j) key[j] = __float_as_uint(norms[t * 16 + j]);  // >0: bits monotone

  unsigned prefix = 0, himask = 0;
  int remaining = KPROM;
  for (int p = 24; p >= 0; p -= 8) {
    for (int i = t; i < 16 * 257; i += 1024) histW[i] = 0;
    __syncthreads();
#pragma unroll
    for (int j = 0; j < 16; ++j)
      if ((key[j] & himask) == prefix) atomicAdd(&histW[w * 257 + ((key[j] >> p) & 255)], 1);
    __syncthreads();
    if (t < 256) {
      int h = 0;
#pragma unroll
      for (int w2 = 0; w2 < 16; ++w2) h += histW[w2 * 257 + t];
      sh[t] = h;
    }
    __syncthreads();
    for (int o = 1; o < 256; o <<= 1) {  // suffix-inclusive sum
      int x = (t < 256 && t + o < 256) ? sh[t + o] : 0;
      __syncthreads();
      if (t < 256) sh[t] += x;
      __syncthreads();
    }
    if (t < 256) {
      int sfex = (t < 255) ? sh[t + 1] : 0;  // count of keys with strictly greater digit
      if (sfex < remaining && remaining <= sh[t]) { s_digit = t; s_sub = sfex; }
    }
    __syncthreads();
    prefix |= ((unsigned)s_digit) << p;
    remaining -= s_sub;
    himask |= (0xFFu << p);
    __syncthreads();
  }
  unsigned T = prefix;  // exact 128th-largest key

  int cgt = 0, ceq = 0;
#pragma unroll
  for (int j = 0; j < 16; ++j) { cgt += (key[j] > T); ceq += (key[j] == T); }
  // single packed scan: gt in high bits, eq in low 15 (sums: 16384<<15 < 2^31; ceq<=16384)
  int total_pk;
  int spk = scan_excl_1024((cgt << 15) | ceq, sh, &total_pk);
  int sgt = spk >> 15, seq = spk & 0x7FFF;
  int total_gt = total_pk >> 15;
  int need_eq = KPROM - total_gt;
  int g = sgt, e = seq;
#pragma unroll
  for (int j = 0; j < 16; ++j) {
    if (key[j] > T) { s_selkey[g] = key[j]; s_selidx[g] = t * 16 + j; ++g; }
    else if (key[j] == T) {
      if (e < need_eq) { s_selkey[total_gt + e] = key[j]; s_selidx[total_gt + e] = t * 16 + j; }
      ++e;
    }
  }
  __syncthreads();
  if (t < KPROM) {  // stable rank: value desc, index asc == lax.top_k
    unsigned mk = s_selkey[t];
    int mi = s_selidx[t];
    int rank = 0;
    for (int q2 = 0; q2 < KPROM; ++q2) {
      unsigned qk = s_selkey[q2];
      int qi = s_selidx[q2];
      rank += (qk > mk || (qk == mk && qi < mi)) ? 1 : 0;
    }
    topidx[rank] = mi;
  }
}

// ============ kBC: 640 blocks, no cross-block deps ============
//  b < 512: out_s copy (1 row/block) + sptr
//  b >= 512: q-block (8 q rows): q[r] = wq[8qb+r].lmean + bq  (2 rows/wave, LDS),
//            then rv += sum_r q[r] * wk[8qb+r][:]  (atomics; rv zeroed by kA)
__global__ void kBC(const float* __restrict__ cand, const float* __restrict__ s_memory,
                    const int* __restrict__ topidx, const int* __restrict__ s_ptr,
                    const float* __restrict__ wq, const float* __restrict__ bq,
                    const float* __restrict__ wk, const float* __restrict__ lmean,
                    float* __restrict__ out_s, float* __restrict__ out_sptr,
                    float* __restrict__ rv) {
  int b = blockIdx.x, t = threadIdx.x, lane = t & 63, w = t >> 6;
  if (b < 512) {
    int sp = s_ptr[0];
    int k = (b - sp + SSZ) & (SSZ - 1);
    const float* src = (k < KPROM) ? (cand + (size_t)topidx[k] * DIMV) : (s_memory + (size_t)b * DIMV);
    ((f32x4*)(out_s + (size_t)b * DIMV))[t] = ((const f32x4*)src)[t];
    if (b == 0 && t == 0) out_sptr[0] = (float)((sp + KPROM) % SSZ);
    return;
  }
  __shared__ float qs[8];
  int qb = b - 512;
  const f32x4* lm = (const f32x4*)lmean;
#pragma unroll
  for (int rr = 0; rr < 2; ++rr) {  // each wave: 2 q rows
    int d = qb * 8 + w * 2 + rr;
    const f32x4* row = (const f32x4*)(wq + (size_t)d * DIMV);
    float s = 0.f;
#pragma unroll
    for (int c = 0; c < 4; ++c) {
      f32x4 a = row[c * 64 + lane], bb = lm[c * 64 + lane];
      s += a.x * bb.x + a.y * bb.y + a.z * bb.z + a.w * bb.w;
    }
    s = wave_sum(s);
    if (lane == 0) qs[w * 2 + rr] = s + bq[d];
  }
  __syncthreads();
  f32x4 a = {0.f, 0.f, 0.f, 0.f};
#pragma unroll
  for (int r = 0; r < 8; ++r) {
    float qd = qs[r];
    f32x4 v = ((const f32x4*)(wk + (size_t)(qb * 8 + r) * DIMV))[t];
    a += v * qd;
  }
  atomicAdd(&rv[t * 4 + 0], a.x);
  atomicAdd(&rv[t * 4 + 1], a.y);
  atomicAdd(&rv[t * 4 + 2], a.z);
  atomicAdd(&rv[t * 4 + 3], a.w);
}

// ============ kD: 128 blk; logit = out_s[row].rv; packed-u64 atomicMax argmax ============
// key = monotone-uint(logit) << 32 | ~row  -> max == first-occurrence argmax.
// (bk.q shift + 1/sqrt(D) scale are argmax-invariant)
__global__ void kD(const float* __restrict__ out_s, const float* __restrict__ rv,
                   unsigned long long* __restrict__ bestPack) {
  __shared__ unsigned long long spk[4];
  int t = threadIdx.x, lane = t & 63, w = t >> 6;
  int srow = blockIdx.x * 4 + w;
  const f32x4* a = (const f32x4*)(out_s + (size_t)srow * DIMV);
  const f32x4* b = (const f32x4*)rv;
  float s = 0.f;
#pragma unroll
  for (int c = 0; c < 4; ++c) {
    f32x4 x = a[c * 64 + lane], y = b[c * 64 + lane];
    s += x.x * y.x + x.y * y.y + x.z * y.z + x.w * y.w;
  }
  s = wave_sum(s);
  if (lane == 0) {
    unsigned u = __float_as_uint(s);
    u = (u & 0x80000000u) ? ~u : (u | 0x80000000u);
    spk[w] = ((unsigned long long)u << 32) | (unsigned)(~srow);
  }
  __syncthreads();
  if (t == 0) {
    unsigned long long m0 = spk[0];
    for (int i = 1; i < 4; ++i)
      if (spk[i] > m0) m0 = spk[i];
    atomicMax(bestPack, m0);
  }
}

// ============ kGs: sims vs candidate (1024 blk, 4 rows/block) + inline cnorm ============
__global__ void kGs(const float* __restrict__ mnorm, const float* __restrict__ m,
                    const float* __restrict__ out_s,
                    const unsigned long long* __restrict__ bestPack,
                    float* __restrict__ sims) {
  int b = blockIdx.x, t = threadIdx.x, lane = t & 63, w = t >> 6;
  int row = b * 4 + w;
  int bi = ~((unsigned)(bestPack[0] & 0xFFFFFFFFull));
  const f32x4* mp = (const f32x4*)(m + (size_t)row * DIMV);
  const f32x4* cp = (const f32x4*)(out_s + (size_t)bi * DIMV);
  float sd = 0.f, cd = 0.f;
#pragma unroll
  for (int c = 0; c < 4; ++c) {
    int i = c * 64 + lane;
    f32x4 v = mp[i], u = cp[i];
    sd += v.x * u.x + v.y * u.y + v.z * u.z + v.w * u.w;
    cd += u.x * u.x + u.y * u.y + u.z * u.z + u.w * u.w;
  }
  sd = wave_sum(sd);
  cd = wave_sum(cd);
  if (lane == 0)
    sims[row] = sd / (fmaxf(mnorm[row], 1e-12f) * fmaxf(sqrtf(cd), 1e-12f));
}

// ============ kH: decide + out_mu + ltier + export control to d_ws (1 blk x 1024) ============
__global__ void kH(const float* __restrict__ pv, const int* __restrict__ pidx,
                   const float* __restrict__ sims, const float* __restrict__ mu,
                   const float* __restrict__ mnorm,
                   const unsigned long long* __restrict__ bestPack,
                   const float* __restrict__ lu, const float* __restrict__ out_s,
                   float* __restrict__ out_mu, float* __restrict__ out_lu,
                   int* __restrict__ ws) {
  __shared__ float swv[16];
  __shared__ int swi[16];
  __shared__ float ssum[16];
  __shared__ int szf[16];
  __shared__ float s_res[2];
  __shared__ int s_resi[2];
  __shared__ int s_branch, s_i1, s_i2, s_lj, s_bi;
  __shared__ float s_u1, s_u2, s_lmean, s_cn;
  int t = threadIdx.x, lane = t & 63, w = t >> 6;

  // 0: decode best + compute cnorm inline
  if (t == 0) s_bi = ~((unsigned)(bestPack[0] & 0xFFFFFFFFull));
  __syncthreads();
  {
    float cs = 0.f;
    if (t < 256) {
      f32x4 c4 = ((const f32x4*)(out_s + (size_t)s_bi * DIMV))[t];
      cs = c4.x * c4.x + c4.y * c4.y + c4.z * c4.z + c4.w * c4.w;
    }
    cs = wave_sum(cs);
    if (lane == 0) ssum[w] = cs;
    __syncthreads();
    if (t == 0) {
      float s2 = 0.f;
      for (int i = 0; i < 16; ++i) s2 += ssum[i];
      s_cn = sqrtf(s2);
    }
    __syncthreads();
  }

  // A: internal pairwise max over 528 block-partials
  float bv = -3.402823466e38f;
  int bidx = 0x7FFFFFFF;
  for (int i = t; i < NPAIR; i += 1024) {
    float v = pv[i];
    int fi = pidx[i];
    if (v > bv || (v == bv && fi < bidx)) { bv = v; bidx = fi; }
  }
  wave_maxidx(bv, bidx);
  if (lane == 0) { swv[w] = bv; swi[w] = bidx; }
  __syncthreads();
  if (t == 0) {
    float a = swv[0]; int ai = swi[0];
    for (int i = 1; i < 16; ++i)
      if (swv[i] > a || (swv[i] == a && swi[i] < ai)) { a = swv[i]; ai = swi[i]; }
    s_res[0] = a; s_resi[0] = ai;
  }
  __syncthreads();

  // B: argmax(sims), first occurrence
  bv = -3.402823466e38f;
  bidx = 0x7FFFFFFF;
#pragma unroll
  for (int j = 0; j < 4; ++j) {
    int i = t * 4 + j;
    float v = sims[i];
    if (v > bv) { bv = v; bidx = i; }
  }
  wave_maxidx(bv, bidx);
  if (lane == 0) { swv[w] = bv; swi[w] = bidx; }
  __syncthreads();
  if (t == 0) {
    float a = swv[0]; int ai = swi[0];
    for (int i = 1; i < 16; ++i)
      if (swv[i] > a || (swv[i] == a && swi[i] < ai)) { a = swv[i]; ai = swi[i]; }
    s_res[1] = a; s_resi[1] = ai;
  }
  __syncthreads();

  // C: mu stats
  float muv[4];
  float sum = 0.f, mnv = 3.402823466e38f;
  int mni = 0x7FFFFFFF, zf = 0;
#pragma unroll
  for (int j = 0; j < 4; ++j) {
    int i = t * 4 + j;
    float v = mu[i];
    muv[j] = v;
    sum += v;
    if (v < mnv) { mnv = v; mni = i; }
    if (v == 0.f) zf = 1;
  }
  sum = wave_sum(sum);
  wave_minidx(mnv, mni);
#pragma unroll
  for (int o = 32; o > 0; o >>= 1) zf |= __shfl_down(zf, o, 64);
  if (lane == 0) { ssum[w] = sum; swv[w] = mnv; swi[w] = mni; szf[w] = zf; }
  __syncthreads();
  if (t == 0) {
    float muSum = 0.f;
    int anyz = 0;
    float a = swv[0]; int li = swi[0];
    for (int i = 0; i < 16; ++i) {
      muSum += ssum[i];
      anyz |= szf[i];
      if (i > 0 && (swv[i] < a || (swv[i] == a && swi[i] < li))) { a = swv[i]; li = swi[i]; }
    }
    float muMean = muSum / 4096.f;
    float internal_sim = s_res[0];
    int iflat = s_resi[0];
    float sim_cand = s_res[1];
    int msi = s_resi[1];
    int branch, i1 = -1, i2 = -1;
    float u1 = 0.f, u2 = 0.f;
    if (anyz) {
      branch = 0; i1 = li; u1 = muMean + 1e-5f;
    } else if (sim_cand > 0.98f) {
      branch = 1; i1 = msi; u1 = (mu[msi] + muMean) * 0.5f;
    } else if (internal_sim > 0.98f) {
      branch = 2; i1 = iflat / MSZ; i2 = iflat - (iflat / MSZ) * MSZ;
      float o1 = mu[i1], o2 = mu[i2];
      u1 = (o1 + o2) * 0.5f;
      u2 = (muSum - o1 + u1) / 4096.f + 1e-5f;  // mean recomputed after idx1 write
    } else {
      if (s_cn > mnorm[li]) { branch = 0; i1 = li; u1 = muMean + 1e-5f; }
      else branch = 4;
    }
    s_branch = branch; s_i1 = i1; s_i2 = i2; s_u1 = u1; s_u2 = u2;
    ws[2] = branch; ws[3] = i1; ws[4] = i2; ws[5] = s_bi;
  }
  __syncthreads();

  // D: write out_mu + argmax of updated mu (first occurrence)
  int branch = s_branch, i1 = s_i1, i2 = s_i2;
  float u1 = s_u1, u2 = s_u2;
  bv = -3.402823466e38f;
  bidx = 0x7FFFFFFF;
#pragma unroll
  for (int j = 0; j < 4; ++j) {
    int i = t * 4 + j;
    float v = muv[j];
    if (branch != 4 && i == i1) v = u1;
    if (branch == 2 && i == i2) v = u2;
    out_mu[i] = v;
    if (v > bv) { bv = v; bidx = i; }
  }
  wave_maxidx(bv, bidx);
  __syncthreads();
  if (lane == 0) { swv[w] = bv; swi[w] = bidx; }
  __syncthreads();
  if (t == 0) {
    float a = swv[0]; int ai = swi[0];
    for (int i = 1; i < 16; ++i)
      if (swv[i] > a || (swv[i] == a && swi[i] < ai)) { a = swv[i]; ai = swi[i]; }
    ws[1] = ai;  // mi
  }

  // E: ltier — lj = argmin(lu) first occurrence, mean(lu) of pre-write values
  float luv[8];
  sum = 0.f; mnv = 3.402823466e38f; mni = 0x7FFFFFFF;
#pragma unroll
  for (int j = 0; j < 8; ++j) {
    int i = t * 8 + j;
    float v = lu[i];
    luv[j] = v;
    sum += v;
    if (v < mnv) { mnv = v; mni = i; }
  }
  sum = wave_sum(sum);
  wave_minidx(mnv, mni);
  __syncthreads();
  if (lane == 0) { swv[w] = mnv; swi[w] = mni; ssum[w] = sum; }
  __syncthreads();
  if (t == 0) {
    float a = swv[0]; int ai = swi[0];
    float ls = 0.f;
    for (int i = 0; i < 16; ++i) {
      ls += ssum[i];
      if (i > 0 && (swv[i] < a || (swv[i] == a && swi[i] < ai))) { a = swv[i]; ai = swi[i]; }
    }
    s_lj = ai;
    s_lmean = ls / 8192.f;
    ws[0] = ai;
  }
  __syncthreads();
  int lj = s_lj;
  float lmv = s_lmean;
#pragma unroll
  for (int j = 0; j < 8; ++j) {
    int i = t * 8 + j;
    out_lu[i] = (i == lj) ? lmv : luv[j];
  }
}

// ============ kI: write_m (1024 blk x 4 rows) + write_l (2048 blk x 4 rows) ============
// Normal groups: 4 independent 16B load+store pairs per thread. Groups containing a
// special row (i1/i2 for m, lj for l) fall back to the per-row path.
__global__ void kI(const float* __restrict__ m, const float* __restrict__ l_memory,
                   const float* __restrict__ out_s, const int* __restrict__ ws,
                   float* __restrict__ out_m, float* __restrict__ out_l) {
  __shared__ float sred[4];
  int b = blockIdx.x, t = threadIdx.x, lane = t & 63, w = t >> 6;
  int lj = ws[0], mi = ws[1], branch = ws[2], i1 = ws[3], i2 = ws[4], best = ws[5];
  if (b < 1024) {  // m tier, rows r0..r0+3
    int r0 = b * 4;
    bool special = (branch != 4) &&
                   ((i1 >= r0 && i1 < r0 + 4) || (branch == 2 && i2 >= r0 && i2 < r0 + 4));
    if (!special) {
      const f32x4* src = (const f32x4*)(m + (size_t)r0 * DIMV);
      f32x4* dst = (f32x4*)(out_m + (size_t)r0 * DIMV);
#pragma unroll
      for (int k = 0; k < 4; ++k) dst[k * 256 + t] = src[k * 256 + t];
      return;
    }
    for (int rr = 0; rr < 4; ++rr) {
      int row = r0 + rr;
      int mode = 0;
      if ((branch == 0 && row == i1) || (branch == 2 && row == i2)) mode = 1;
      else if (branch == 1 && row == i1) mode = 2;
      else if (branch == 2 && row == i1) mode = 3;
      f32x4* dst = (f32x4*)(out_m + (size_t)row * DIMV);
      if (mode == 0) {
        dst[t] = ((const f32x4*)(m + (size_t)row * DIMV))[t];
      } else if (mode == 1) {
        dst[t] = ((const f32x4*)(out_s + (size_t)best * DIMV))[t];
      } else {
        f32x4 a = ((const f32x4*)(m + (size_t)row * DIMV))[t];
        f32x4 bb = (mode == 2) ? ((const f32x4*)(out_s + (size_t)best * DIMV))[t]
                               : ((const f32x4*)(m + (size_t)i2 * DIMV))[t];
        f32x4 v = (a + bb) * 0.5f;
        float ss = v.x * v.x + v.y * v.y + v.z * v.z + v.w * v.w;
        ss = wave_sum(ss);
        if (lane == 0) sred[w] = ss;
        __syncthreads();
        float nrm = fmaxf(sqrtf(sred[0] + sred[1] + sred[2] + sred[3]), 1e-12f);
        __syncthreads();  // sred reusable by later iterations
        dst[t] = v / nrm;
      }
    }
  } else {  // l tier, rows r0..r0+3
    int r0 = (b - 1024) * 4;
    bool special = (lj >= r0 && lj < r0 + 4);
    if (!special) {
      const f32x4* src = (const f32x4*)(l_memory + (size_t)r0 * DIMV);
      f32x4* dst = (f32x4*)(out_l + (size_t)r0 * DIMV);
#pragma unroll
      for (int k = 0; k < 4; ++k) dst[k * 256 + t] = src[k * 256 + t];
      return;
    }
    for (int rr = 0; rr < 4; ++rr) {
      int row = r0 + rr;
      f32x4 v = ((const f32x4*)(l_memory + (size_t)row * DIMV))[t];
      if (row == lj) {
        // recompute out_m[mi] inline (avoids cross-block dependency on out_m)
        int mode = 0;
        if ((branch == 0 && mi == i1) || (branch == 2 && mi == i2)) mode = 1;
        else if (branch == 1 && mi == i1) mode = 2;
        else if (branch == 2 && mi == i1) mode = 3;
        f32x4 mv;
        if (mode == 0) {
          mv = ((const f32x4*)(m + (size_t)mi * DIMV))[t];
        } else if (mode == 1) {
          mv = ((const f32x4*)(out_s + (size_t)best * DIMV))[t];
        } else {
          f32x4 a = ((const f32x4*)(m + (size_t)mi * DIMV))[t];
          f32x4 bb = (mode == 2) ? ((const f32x4*)(out_s + (size_t)best * DIMV))[t]
                                 : ((const f32x4*)(m + (size_t)i2 * DIMV))[t];
          f32x4 vm = (a + bb) * 0.5f;
          float ss = vm.x * vm.x + vm.y * vm.y + vm.z * vm.z + vm.w * vm.w;
          ss = wave_sum(ss);
          if (lane == 0) sred[w] = ss;
          __syncthreads();
          float nrm = fmaxf(sqrtf(sred[0] + sred[1] + sred[2] + sred[3]), 1e-12f);
          __syncthreads();
          mv = vm / nrm;
        }
        v = v * 0.9f + mv * 0.1f;
      }
      ((f32x4*)(out_l + (size_t)row * DIMV))[t] = v;
    }
  }
}

extern "C" void kernel_launch(void* const* d_in, const int* in_sizes, int n_in,
                              void* d_out, int out_size, void* d_ws, size_t ws_size,
                              hipStream_t stream) {
  const float* cand = (const float*)d_in[0];
  const float* s_memory = (const float*)d_in[1];
  const float* m_memory = (const float*)d_in[2];
  const float* l_memory = (const float*)d_in[3];
  const float* m_utility = (const float*)d_in[4];
  const float* l_utility = (const float*)d_in[5];
  const float* wq = (const float*)d_in[6];
  const float* bq = (const float*)d_in[7];
  const float* wk = (const float*)d_in[8];
  const float* bk = (const float*)d_in[9];
  const int* s_ptr = (const int*)d_in[10];
  (void)bk;  // bk.q is a constant logit shift -> argmax-invariant

  float* out = (float*)d_out;
  float* out_s = out + OUT_S;
  float* out_m = out + OUT_M;
  float* out_l = out + OUT_L;
  float* out_mu = out + OUT_MU;
  float* out_lu = out + OUT_LU;
  float* out_sptr = out + OUT_SPTR;

  float* lsc = out_l;  // scratch region: fully consumed before kI overwrites it
  unsigned short* mb = (unsigned short*)(lsc + SC_BF16);
  float* norms = lsc + SC_NORMS;
  int* topidx = (int*)(lsc + SC_TOPIDX);
  float* lpart = lsc + SC_LPART;
  float* rv = lsc + SC_RV;
  float* lmean = lsc + SC_LMEAN;
  unsigned long long* bestPack = (unsigned long long*)(lsc + SC_BPK);
  float* mnorm = lsc + SC_MNORM;
  float* sims = lsc + SC_SIMS;
  float* pv = lsc + SC_PPV;
  int* pidx = (int*)(lsc + SC_PPI);
  int* wsctl = (int*)d_ws;  // 24 B control block, read by kI after scratch is dead

  kA<<<1408, 256, 0, stream>>>(cand, l_memory, m_memory, norms, lpart, mb, mnorm, rv, bestPack);
  kTG<<<NPAIR + 2, 1024, 0, stream>>>(norms, topidx, lpart, lmean, mb, mnorm, pv, pidx);
  kBC<<<640, 256, 0, stream>>>(cand, s_memory, topidx, s_ptr, wq, bq, wk, lmean, out_s, out_sptr,
                               rv);
  kD<<<128, 256, 0, stream>>>(out_s, rv, bestPack);
  kGs<<<1024, 256, 0, stream>>>(mnorm, m_memory, out_s, bestPack, sims);
  kH<<<1, 1024, 0, stream>>>(pv, pidx, sims, m_utility, mnorm, bestPack, l_utility, out_s,
                             out_mu, out_lu, wsctl);
  kI<<<3072, 256, 0, stream>>>(m_memory, l_memory, out_s, wsctl, out_m, out_l);
}

// Round 12
// 276.860 us; speedup vs baseline: 1.0624x; 1.0624x over previous
//
#include <hip/hip_runtime.h>

#define DIMV 1024
#define SSZ 512
#define MSZ 4096
#define LSZ 8192
#define KPROM 128
#define NCAND 16384
#define NPAIR 528  // 128x128 tiles over lower triangle incl diagonal: 32*33/2

typedef __attribute__((ext_vector_type(4))) float f32x4;
typedef __attribute__((ext_vector_type(4))) unsigned int u32x4;
typedef __attribute__((ext_vector_type(4))) unsigned short u16x4;
typedef __attribute__((ext_vector_type(8))) __bf16 bf16x8;

// ---------------- output layout (float element offsets) ----------------
#define OUT_S 0ull
#define OUT_M 524288ull
#define OUT_L 4718592ull
#define OUT_MU 13107200ull
#define OUT_LU 13111296ull
#define OUT_SPTR 13119488ull

// ---- scratch inside out_l region (8,388,608 floats; erased last by kI) ----
#define SC_BF16 0ull          // 4096x1024 bf16 (2,097,152 float slots)
#define SC_NORMS 2100000ull   // 16384
#define SC_TOPIDX 2117000ull  // 128 ints
#define SC_LPART 2120000ull   // 128*1024
#define SC_RV 2260000ull      // 1024 (zeroed by kA block 0)
#define SC_LMEAN 2262000ull   // 1024
#define SC_LOGITS 2413000ull  // 512
#define SC_BEST 2414000ull    // [0] int best_s_idx, [1] float cnorm
#define SC_MNORM 2415000ull   // 4096
#define SC_SIMS 2420000ull    // 4096
#define SC_PPV 2425000ull     // 528 partial max vals
#define SC_PPI 2427000ull     // 528 partial max flat idx

__device__ __forceinline__ float wave_sum(float v) {
#pragma unroll
  for (int o = 32; o > 0; o >>= 1) v += __shfl_down(v, o, 64);
  return v;
}
__device__ __forceinline__ void wave_maxidx(float& v, int& i) {
#pragma unroll
  for (int o = 32; o > 0; o >>= 1) {
    float ov = __shfl_down(v, o, 64);
    int oi = __shfl_down(i, o, 64);
    if (ov > v || (ov == v && oi < i)) { v = ov; i = oi; }
  }
}
__device__ __forceinline__ void wave_minidx(float& v, int& i) {
#pragma unroll
  for (int o = 32; o > 0; o >>= 1) {
    float ov = __shfl_down(v, o, 64);
    int oi = __shfl_down(i, o, 64);
    if (ov < v || (ov == v && oi < i)) { v = ov; i = oi; }
  }
}
__device__ __forceinline__ unsigned short f2bf(float x) {  // RNE float->bf16
  unsigned u = __float_as_uint(x);
  return (unsigned short)((u + 0x7FFFu + ((u >> 16) & 1u)) >> 16);
}
// async global->LDS, 16B per lane; LDS dest = wave-uniform base + lane*16
__device__ __forceinline__ void gload16(const unsigned short* g, unsigned short* l) {
  __builtin_amdgcn_global_load_lds((const __attribute__((address_space(1))) unsigned int*)(g),
                                   (__attribute__((address_space(3))) unsigned int*)(l), 16, 0, 0);
}

// ============ kA: l-part (128 blk) + cand norms (1024 blk, 16 rows)
// ============     + bf16 M + mnorm (256 blk, 16 rows). Block 0 also zeroes rv.
__global__ void kA(const float* __restrict__ cand, const float* __restrict__ l_memory,
                   const float* __restrict__ m, float* __restrict__ norms,
                   float* __restrict__ lpart, unsigned short* __restrict__ mb,
                   float* __restrict__ mnorm, float* __restrict__ rv) {
  int b = blockIdx.x, t = threadIdx.x, lane = t & 63, w = t >> 6;
  if (b < 128) {  // l column partial sums, 64 rows/block, 4 independent accumulators
    if (b == 0) {  // zero rv for kBC's atomics (kA completes before kBC: stream order)
      f32x4 z = {0.f, 0.f, 0.f, 0.f};
      ((f32x4*)rv)[t] = z;
    }
    f32x4 a0 = {0.f, 0.f, 0.f, 0.f}, a1 = a0, a2 = a0, a3 = a0;
    const f32x4* base = (const f32x4*)(l_memory + (size_t)b * 64 * DIMV);
#pragma unroll 4
    for (int r = 0; r < 64; r += 4) {
      a0 += base[(r + 0) * 256 + t];
      a1 += base[(r + 1) * 256 + t];
      a2 += base[(r + 2) * 256 + t];
      a3 += base[(r + 3) * 256 + t];
    }
    f32x4 a = (a0 + a1) + (a2 + a3);
    ((f32x4*)(lpart + (size_t)b * DIMV))[t] = a;
  } else if (b < 1152) {  // candidate row norms, 16 rows/block (4 rows/wave)
    int r0 = (b - 128) * 16 + w * 4;
    const f32x4* base4 = (const f32x4*)(cand + (size_t)r0 * DIMV);
    float s0 = 0.f, s1 = 0.f, s2 = 0.f, s3 = 0.f;
#pragma unroll
    for (int k = 0; k < 16; ++k) {
      f32x4 v = base4[k * 64 + lane];
      float d = v.x * v.x + v.y * v.y + v.z * v.z + v.w * v.w;
      if (k < 4) s0 += d;
      else if (k < 8) s1 += d;
      else if (k < 12) s2 += d;
      else s3 += d;
    }
    f32x4 sv = {s0, s1, s2, s3};
#pragma unroll
    for (int o = 32; o > 0; o >>= 1) {
      sv.x += __shfl_down(sv.x, o, 64);
      sv.y += __shfl_down(sv.y, o, 64);
      sv.z += __shfl_down(sv.z, o, 64);
      sv.w += __shfl_down(sv.w, o, 64);
    }
    if (lane == 0) {
      f32x4 o4 = {sqrtf(sv.x), sqrtf(sv.y), sqrtf(sv.z), sqrtf(sv.w)};
      *((f32x4*)(norms + r0)) = o4;
    }
  } else {  // m -> bf16 + row norms, 16 rows/block (4 rows/wave)
    int r0 = (b - 1152) * 16 + w * 4;
    const f32x4* base4 = (const f32x4*)(m + (size_t)r0 * DIMV);
    u16x4* mb4 = (u16x4*)(mb + (size_t)r0 * DIMV);
    float s0 = 0.f, s1 = 0.f, s2 = 0.f, s3 = 0.f;
#pragma unroll
    for (int k = 0; k < 16; ++k) {
      int i = k * 64 + lane;
      f32x4 v = base4[i];
      float d = v.x * v.x + v.y * v.y + v.z * v.z + v.w * v.w;
      if (k < 4) s0 += d;
      else if (k < 8) s1 += d;
      else if (k < 12) s2 += d;
      else s3 += d;
      u16x4 h;
      h.x = f2bf(v.x); h.y = f2bf(v.y); h.z = f2bf(v.z); h.w = f2bf(v.w);
      mb4[i] = h;
    }
    f32x4 sv = {s0, s1, s2, s3};
#pragma unroll
    for (int o = 32; o > 0; o >>= 1) {
      sv.x += __shfl_down(sv.x, o, 64);
      sv.y += __shfl_down(sv.y, o, 64);
      sv.z += __shfl_down(sv.z, o, 64);
      sv.w += __shfl_down(sv.w, o, 64);
    }
    if (lane == 0) {
      f32x4 o4 = {sqrtf(sv.x), sqrtf(sv.y), sqrtf(sv.z), sqrtf(sv.w)};
      *((f32x4*)(mnorm + r0)) = o4;
    }
  }
}

// ============ kT: blk0 = exact stable top-128 (8-bit radix, per-wave histograms),
// ============     blk1 = lmean final (ILP-4). Both blocks run concurrently. ============
__device__ int scan_excl_1024(int v, int* sh, int* total) {
  int t = threadIdx.x;
  sh[t] = v;
  __syncthreads();
  for (int o = 1; o < 1024; o <<= 1) {
    int x = (t >= o) ? sh[t - o] : 0;
    __syncthreads();
    sh[t] += x;
    __syncthreads();
  }
  int incl = sh[t];
  *total = sh[1023];
  __syncthreads();
  return incl - v;
}

__global__ void kT(const float* __restrict__ norms, int* __restrict__ topidx,
                   const float* __restrict__ lpart, float* __restrict__ lmean) {
  int t = threadIdx.x;
  if (blockIdx.x == 1) {  // lmean: reduce 128 partials per column, 4 indep accumulators
    float s0 = 0.f, s1 = 0.f, s2 = 0.f, s3 = 0.f;
    for (int p = 0; p < 128; p += 4) {
      s0 += lpart[(size_t)(p + 0) * DIMV + t];
      s1 += lpart[(size_t)(p + 1) * DIMV + t];
      s2 += lpart[(size_t)(p + 2) * DIMV + t];
      s3 += lpart[(size_t)(p + 3) * DIMV + t];
    }
    lmean[t] = ((s0 + s1) + (s2 + s3)) * (1.f / 8192.f);
    return;
  }
  int w = t >> 6;
  __shared__ int sh[1024];
  __shared__ int histW[16][256];
  __shared__ unsigned s_selkey[KPROM];
  __shared__ int s_selidx[KPROM];
  __shared__ int s_digit, s_sub;
  unsigned key[16];
#pragma unroll
  for (int j = 0; j < 16; ++j) key[j] = __float_as_uint(norms[t * 16 + j]);  // >0: bits monotone

  unsigned prefix = 0, himask = 0;
  int remaining = KPROM;
  for (int p = 24; p >= 0; p -= 8) {
#pragma unroll
    for (int i = 0; i < 4; ++i) ((int*)histW)[t + i * 1024] = 0;
    __syncthreads();
#pragma unroll
    for (int j = 0; j < 16; ++j)
      if ((key[j] & himask) == prefix) atomicAdd(&histW[w][(key[j] >> p) & 255], 1);
    __syncthreads();
    if (t < 256) {
      int h = 0;
#pragma unroll
      for (int w2 = 0; w2 < 16; ++w2) h += histW[w2][t];
      sh[t] = h;
    }
    __syncthreads();
    for (int o = 1; o < 256; o <<= 1) {  // suffix-inclusive sum
      int x = (t < 256 && t + o < 256) ? sh[t + o] : 0;
      __syncthreads();
      if (t < 256) sh[t] += x;
      __syncthreads();
    }
    if (t < 256) {
      int sfex = (t < 255) ? sh[t + 1] : 0;  // count of keys with strictly greater digit
      if (sfex < remaining && remaining <= sh[t]) { s_digit = t; s_sub = sfex; }
    }
    __syncthreads();
    prefix |= ((unsigned)s_digit) << p;
    remaining -= s_sub;
    himask |= (0xFFu << p);
    __syncthreads();
  }
  unsigned T = prefix;  // exact 128th-largest key

  int cgt = 0, ceq = 0;
#pragma unroll
  for (int j = 0; j < 16; ++j) { cgt += (key[j] > T); ceq += (key[j] == T); }
  int total_gt, total_eq;
  int sgt = scan_excl_1024(cgt, sh, &total_gt);
  int seq = scan_excl_1024(ceq, sh, &total_eq);
  int need_eq = KPROM - total_gt;
  int g = sgt, e = seq;
#pragma unroll
  for (int j = 0; j < 16; ++j) {
    if (key[j] > T) { s_selkey[g] = key[j]; s_selidx[g] = t * 16 + j; ++g; }
    else if (key[j] == T) {
      if (e < need_eq) { s_selkey[total_gt + e] = key[j]; s_selidx[total_gt + e] = t * 16 + j; }
      ++e;
    }
  }
  __syncthreads();
  if (t < KPROM) {  // stable rank: value desc, index asc == lax.top_k
    unsigned mk = s_selkey[t];
    int mi = s_selidx[t];
    int rank = 0;
    for (int q2 = 0; q2 < KPROM; ++q2) {
      unsigned qk = s_selkey[q2];
      int qi = s_selidx[q2];
      rank += (qk > mk || (qk == mk && qi < mi)) ? 1 : 0;
    }
    topidx[rank] = mi;
  }
}

// ============ kBC: 640 blocks, no cross-block deps ============
//  b < 512: out_s copy (1 row/block) + sptr
//  b >= 512: q-block (8 q rows): q[r] = wq[8qb+r].lmean + bq  (2 rows/wave, LDS),
//            then rv += sum_r q[r] * wk[8qb+r][:]  (atomics; rv zeroed by kA)
__global__ void kBC(const float* __restrict__ cand, const float* __restrict__ s_memory,
                    const int* __restrict__ topidx, const int* __restrict__ s_ptr,
                    const float* __restrict__ wq, const float* __restrict__ bq,
                    const float* __restrict__ wk, const float* __restrict__ lmean,
                    float* __restrict__ out_s, float* __restrict__ out_sptr,
                    float* __restrict__ rv) {
  int b = blockIdx.x, t = threadIdx.x, lane = t & 63, w = t >> 6;
  if (b < 512) {
    int sp = s_ptr[0];
    int k = (b - sp + SSZ) & (SSZ - 1);
    const float* src = (k < KPROM) ? (cand + (size_t)topidx[k] * DIMV) : (s_memory + (size_t)b * DIMV);
    ((f32x4*)(out_s + (size_t)b * DIMV))[t] = ((const f32x4*)src)[t];
    if (b == 0 && t == 0) out_sptr[0] = (float)((sp + KPROM) % SSZ);
    return;
  }
  __shared__ float qs[8];
  int qb = b - 512;
  const f32x4* lm = (const f32x4*)lmean;
#pragma unroll
  for (int rr = 0; rr < 2; ++rr) {  // each wave: 2 q rows
    int d = qb * 8 + w * 2 + rr;
    const f32x4* row = (const f32x4*)(wq + (size_t)d * DIMV);
    float s = 0.f;
#pragma unroll
    for (int c = 0; c < 4; ++c) {
      f32x4 a = row[c * 64 + lane], bb = lm[c * 64 + lane];
      s += a.x * bb.x + a.y * bb.y + a.z * bb.z + a.w * bb.w;
    }
    s = wave_sum(s);
    if (lane == 0) qs[w * 2 + rr] = s + bq[d];
  }
  __syncthreads();
  f32x4 a = {0.f, 0.f, 0.f, 0.f};
#pragma unroll
  for (int r = 0; r < 8; ++r) {
    float qd = qs[r];
    f32x4 v = ((const f32x4*)(wk + (size_t)(qb * 8 + r) * DIMV))[t];
    a += v * qd;
  }
  atomicAdd(&rv[t * 4 + 0], a.x);
  atomicAdd(&rv[t * 4 + 1], a.y);
  atomicAdd(&rv[t * 4 + 2], a.z);
  atomicAdd(&rv[t * 4 + 3], a.w);
}

// ============ kD: logits[s] = s_mem[s].rv  (bk.q shift + 1/sqrt(D) scale are argmax-invariant) ============
__global__ void kD(const float* __restrict__ out_s, const float* __restrict__ rv,
                   float* __restrict__ logits) {
  int lane = threadIdx.x & 63, w = threadIdx.x >> 6;
  int srow = blockIdx.x * 4 + w;
  const f32x4* a = (const f32x4*)(out_s + (size_t)srow * DIMV);
  const f32x4* b = (const f32x4*)rv;
  float s = 0.f;
#pragma unroll
  for (int c = 0; c < 4; ++c) {
    f32x4 x = a[c * 64 + lane], y = b[c * 64 + lane];
    s += x.x * y.x + x.y * y.y + x.z * y.z + x.w * y.w;
  }
  s = wave_sum(s);
  if (lane == 0) logits[srow] = s;
}

// ============ kE: best = argmax(logits); cnorm = ||s_mem[best]|| ============
__global__ void kE(const float* __restrict__ logits, const float* __restrict__ out_s,
                   int* __restrict__ best, float* __restrict__ cnorm) {
  __shared__ float swv[4];
  __shared__ int swi[4];
  int t = threadIdx.x, lane = t & 63, w = t >> 6;
  float v0 = logits[t], v1 = logits[t + 256];
  float bv;
  int bidx;
  if (v1 > v0) { bv = v1; bidx = t + 256; } else { bv = v0; bidx = t; }
  wave_maxidx(bv, bidx);
  if (lane == 0) { swv[w] = bv; swi[w] = bidx; }
  __syncthreads();
  if (t == 0) {
    float a = swv[0]; int ai = swi[0];
    for (int i = 1; i < 4; ++i)
      if (swv[i] > a || (swv[i] == a && swi[i] < ai)) { a = swv[i]; ai = swi[i]; }
    best[0] = ai;
  }
  __syncthreads();
  int bi = best[0];
  f32x4 c4 = ((const f32x4*)(out_s + (size_t)bi * DIMV))[t];
  float s = c4.x * c4.x + c4.y * c4.y + c4.z * c4.z + c4.w * c4.w;
  s = wave_sum(s);
  __syncthreads();
  if (lane == 0) swv[w] = s;
  __syncthreads();
  if (t == 0) cnorm[0] = sqrtf(swv[0] + swv[1] + swv[2] + swv[3]);
}

// ============ kG: pairmax (528 blk, 128x128 tiles, m97-structure) + sims vs candidate (1024 blk) ============
__global__ __launch_bounds__(256, 3) void kG(const unsigned short* __restrict__ mb,
                                             const float* __restrict__ mnorm,
                                             const float* __restrict__ m,
                                             const float* __restrict__ out_s,
                                             const int* __restrict__ best,
                                             const float* __restrict__ cnorm,
                                             float* __restrict__ pv, int* __restrict__ pidx,
                                             float* __restrict__ sims) {
  int b = blockIdx.x, t = threadIdx.x, lane = t & 63, w = t >> 6;
  if (b >= NPAIR) {  // sims: fp32 dot vs candidate, 4 rows/block
    int row = (b - NPAIR) * 4 + w;
    const f32x4* mp = (const f32x4*)(m + (size_t)row * DIMV);
    const f32x4* cp = (const f32x4*)(out_s + (size_t)best[0] * DIMV);
    float sd = 0.f;
#pragma unroll
    for (int c = 0; c < 4; ++c) {
      int i = c * 64 + lane;
      f32x4 v = mp[i], u = cp[i];
      sd += v.x * u.x + v.y * u.y + v.z * u.z + v.w * u.w;
    }
    sd = wave_sum(sd);
    if (lane == 0) sims[row] = sd / (fmaxf(mnorm[row], 1e-12f) * fmaxf(cnorm[0], 1e-12f));
    return;
  }
  __shared__ unsigned short Ash[128 * 64];  // 16 KB, linear + XOR-chunk swizzle
  __shared__ unsigned short Bsh[128 * 64];  // 16 KB
  __shared__ float spv[4];
  __shared__ int spi[4];

  // XCD-contiguous tile order (bijective: 528 = 8*66), then lower-tri decode
  int bs = (b & 7) * 66 + (b >> 3);
  int bi = (int)((sqrtf(8.f * (float)bs + 1.f) - 1.f) * 0.5f);
  while (bi * (bi + 1) / 2 > bs) --bi;
  while ((bi + 1) * (bi + 2) / 2 <= bs) ++bi;
  int bj = bs - bi * (bi + 1) / 2;
  int rowA0 = bi * 128, rowB0 = bj * 128;

  int wr = w >> 1, wc = w & 1;          // wave -> 64x64 quadrant
  int rl = lane & 15, kq4 = lane >> 4;  // fragment row/col + k-group
  int swz = rl & 7;                     // read-side XOR key
  int subrow = lane >> 3, gg = lane & 7;
  int gsw = (gg ^ subrow) << 3;  // source-side XOR'd chunk, in shorts

  f32x4 acc[4][4];
  f32x4 z = {0.f, 0.f, 0.f, 0.f};
#pragma unroll
  for (int ti = 0; ti < 4; ++ti)
#pragma unroll
    for (int tj = 0; tj < 4; ++tj) acc[ti][tj] = z;

  for (int kc = 0; kc < DIMV; kc += 64) {
#pragma unroll
    for (int jj = 0; jj < 4; ++jj) {
      int rsub = w * 32 + jj * 8 + subrow;
      gload16(mb + (size_t)(rowA0 + rsub) * DIMV + kc + gsw, Ash + (w * 4 + jj) * 512);
      gload16(mb + (size_t)(rowB0 + rsub) * DIMV + kc + gsw, Bsh + (w * 4 + jj) * 512);
    }
    __syncthreads();
#pragma unroll
    for (int ks = 0; ks < 2; ++ks) {
      int co = (((ks * 4 + kq4) ^ swz) << 3);
      bf16x8 af[4], bfv[4];
#pragma unroll
      for (int ti = 0; ti < 4; ++ti)
        af[ti] = *(const bf16x8*)(Ash + (wr * 64 + ti * 16 + rl) * 64 + co);
#pragma unroll
      for (int tj = 0; tj < 4; ++tj)
        bfv[tj] = *(const bf16x8*)(Bsh + (wc * 64 + tj * 16 + rl) * 64 + co);
#pragma unroll
      for (int ti = 0; ti < 4; ++ti)
#pragma unroll
        for (int tj = 0; tj < 4; ++tj)
          acc[ti][tj] = __builtin_amdgcn_mfma_f32_16x16x32_bf16(af[ti], bfv[tj], acc[ti][tj], 0, 0, 0);
    }
    __syncthreads();
  }

  float ni[16], nj4[4];
#pragma unroll
  for (int ti = 0; ti < 4; ++ti)
#pragma unroll
    for (int r = 0; r < 4; ++r)
      ni[ti * 4 + r] = fmaxf(mnorm[rowA0 + wr * 64 + ti * 16 + kq4 * 4 + r], 1e-12f);
#pragma unroll
  for (int tj = 0; tj < 4; ++tj)
    nj4[tj] = fmaxf(mnorm[rowB0 + wc * 64 + tj * 16 + rl], 1e-12f);

  float bv = -3.402823466e38f;
  int bidx = 0x7FFFFFFF;
#pragma unroll
  for (int ti = 0; ti < 4; ++ti)
#pragma unroll
    for (int tj = 0; tj < 4; ++tj)
#pragma unroll
      for (int r = 0; r < 4; ++r) {
        int gi = rowA0 + wr * 64 + ti * 16 + kq4 * 4 + r;
        int gj = rowB0 + wc * 64 + tj * 16 + rl;
        if (gi > gj) {
          float s = acc[ti][tj][r] / (ni[ti * 4 + r] * nj4[tj]);
          int fi = gi * MSZ + gj;
          if (s > bv || (s == bv && fi < bidx)) { bv = s; bidx = fi; }
        }
      }
  wave_maxidx(bv, bidx);
  if (lane == 0) { spv[w] = bv; spi[w] = bidx; }
  __syncthreads();
  if (t == 0) {
    float a = spv[0]; int ai = spi[0];
    for (int i = 1; i < 4; ++i)
      if (spv[i] > a || (spv[i] == a && spi[i] < ai)) { a = spv[i]; ai = spi[i]; }
    pv[b] = a;
    pidx[b] = ai;
  }
}

// ============ kH: decide + out_mu + ltier + export control to d_ws (1 blk x 1024) ============
__global__ void kH(const float* __restrict__ pv, const int* __restrict__ pidx,
                   const float* __restrict__ sims, const float* __restrict__ mu,
                   const float* __restrict__ mnorm, const float* __restrict__ cnorm,
                   const int* __restrict__ best, const float* __restrict__ lu,
                   float* __restrict__ out_mu, float* __restrict__ out_lu,
                   int* __restrict__ ws) {
  __shared__ float swv[16];
  __shared__ int swi[16];
  __shared__ float ssum[16];
  __shared__ int szf[16];
  __shared__ float s_res[2];
  __shared__ int s_resi[2];
  __shared__ int s_branch, s_i1, s_i2, s_lj;
  __shared__ float s_u1, s_u2, s_lmean;
  int t = threadIdx.x, lane = t & 63, w = t >> 6;

  // A: internal pairwise max over 528 block-partials
  float bv = -3.402823466e38f;
  int bidx = 0x7FFFFFFF;
  for (int i = t; i < NPAIR; i += 1024) {
    float v = pv[i];
    int fi = pidx[i];
    if (v > bv || (v == bv && fi < bidx)) { bv = v; bidx = fi; }
  }
  wave_maxidx(bv, bidx);
  if (lane == 0) { swv[w] = bv; swi[w] = bidx; }
  __syncthreads();
  if (t == 0) {
    float a = swv[0]; int ai = swi[0];
    for (int i = 1; i < 16; ++i)
      if (swv[i] > a || (swv[i] == a && swi[i] < ai)) { a = swv[i]; ai = swi[i]; }
    s_res[0] = a; s_resi[0] = ai;
  }
  __syncthreads();

  // B: argmax(sims), first occurrence
  bv = -3.402823466e38f;
  bidx = 0x7FFFFFFF;
#pragma unroll
  for (int j = 0; j < 4; ++j) {
    int i = t * 4 + j;
    float v = sims[i];
    if (v > bv) { bv = v; bidx = i; }
  }
  wave_maxidx(bv, bidx);
  if (lane == 0) { swv[w] = bv; swi[w] = bidx; }
  __syncthreads();
  if (t == 0) {
    float a = swv[0]; int ai = swi[0];
    for (int i = 1; i < 16; ++i)
      if (swv[i] > a || (swv[i] == a && swi[i] < ai)) { a = swv[i]; ai = swi[i]; }
    s_res[1] = a; s_resi[1] = ai;
  }
  __syncthreads();

  // C: mu stats
  float muv[4];
  float sum = 0.f, mnv = 3.402823466e38f;
  int mni = 0x7FFFFFFF, zf = 0;
#pragma unroll
  for (int j = 0; j < 4; ++j) {
    int i = t * 4 + j;
    float v = mu[i];
    muv[j] = v;
    sum += v;
    if (v < mnv) { mnv = v; mni = i; }
    if (v == 0.f) zf = 1;
  }
  sum = wave_sum(sum);
  wave_minidx(mnv, mni);
#pragma unroll
  for (int o = 32; o > 0; o >>= 1) zf |= __shfl_down(zf, o, 64);
  if (lane == 0) { ssum[w] = sum; swv[w] = mnv; swi[w] = mni; szf[w] = zf; }
  __syncthreads();
  if (t == 0) {
    float muSum = 0.f;
    int anyz = 0;
    float a = swv[0]; int li = swi[0];
    for (int i = 0; i < 16; ++i) {
      muSum += ssum[i];
      anyz |= szf[i];
      if (i > 0 && (swv[i] < a || (swv[i] == a && swi[i] < li))) { a = swv[i]; li = swi[i]; }
    }
    float muMean = muSum / 4096.f;
    float internal_sim = s_res[0];
    int iflat = s_resi[0];
    float sim_cand = s_res[1];
    int msi = s_resi[1];
    int branch, i1 = -1, i2 = -1;
    float u1 = 0.f, u2 = 0.f;
    if (anyz) {
      branch = 0; i1 = li; u1 = muMean + 1e-5f;
    } else if (sim_cand > 0.98f) {
      branch = 1; i1 = msi; u1 = (mu[msi] + muMean) * 0.5f;
    } else if (internal_sim > 0.98f) {
      branch = 2; i1 = iflat / MSZ; i2 = iflat - (iflat / MSZ) * MSZ;
      float o1 = mu[i1], o2 = mu[i2];
      u1 = (o1 + o2) * 0.5f;
      u2 = (muSum - o1 + u1) / 4096.f + 1e-5f;  // mean recomputed after idx1 write
    } else {
      if (cnorm[0] > mnorm[li]) { branch = 0; i1 = li; u1 = muMean + 1e-5f; }
      else branch = 4;
    }
    s_branch = branch; s_i1 = i1; s_i2 = i2; s_u1 = u1; s_u2 = u2;
    ws[2] = branch; ws[3] = i1; ws[4] = i2; ws[5] = best[0];
  }
  __syncthreads();

  // D: write out_mu + argmax of updated mu (first occurrence)
  int branch = s_branch, i1 = s_i1, i2 = s_i2;
  float u1 = s_u1, u2 = s_u2;
  bv = -3.402823466e38f;
  bidx = 0x7FFFFFFF;
#pragma unroll
  for (int j = 0; j < 4; ++j) {
    int i = t * 4 + j;
    float v = muv[j];
    if (branch != 4 && i == i1) v = u1;
    if (branch == 2 && i == i2) v = u2;
    out_mu[i] = v;
    if (v > bv) { bv = v; bidx = i; }
  }
  wave_maxidx(bv, bidx);
  __syncthreads();
  if (lane == 0) { swv[w] = bv; swi[w] = bidx; }
  __syncthreads();
  if (t == 0) {
    float a = swv[0]; int ai = swi[0];
    for (int i = 1; i < 16; ++i)
      if (swv[i] > a || (swv[i] == a && swi[i] < ai)) { a = swv[i]; ai = swi[i]; }
    ws[1] = ai;  // mi
  }

  // E: ltier — lj = argmin(lu) first occurrence, mean(lu) of pre-write values
  float luv[8];
  sum = 0.f; mnv = 3.402823466e38f; mni = 0x7FFFFFFF;
#pragma unroll
  for (int j = 0; j < 8; ++j) {
    int i = t * 8 + j;
    float v = lu[i];
    luv[j] = v;
    sum += v;
    if (v < mnv) { mnv = v; mni = i; }
  }
  sum = wave_sum(sum);
  wave_minidx(mnv, mni);
  __syncthreads();
  if (lane == 0) { swv[w] = mnv; swi[w] = mni; ssum[w] = sum; }
  __syncthreads();
  if (t == 0) {
    float a = swv[0]; int ai = swi[0];
    float ls = 0.f;
    for (int i = 0; i < 16; ++i) {
      ls += ssum[i];
      if (i > 0 && (swv[i] < a || (swv[i] == a && swi[i] < ai))) { a = swv[i]; ai = swi[i]; }
    }
    s_lj = ai;
    s_lmean = ls / 8192.f;
    ws[0] = ai;
  }
  __syncthreads();
  int lj = s_lj;
  float lmv = s_lmean;
#pragma unroll
  for (int j = 0; j < 8; ++j) {
    int i = t * 8 + j;
    out_lu[i] = (i == lj) ? lmv : luv[j];
  }
}

// ============ kI: write_m (1024 blk x 4 rows) + write_l (2048 blk x 4 rows) ============
// Normal groups: 4 independent 16B load+store pairs per thread. Groups containing a
// special row (i1/i2 for m, lj for l) fall back to the per-row path.
__global__ void kI(const float* __restrict__ m, const float* __restrict__ l_memory,
                   const float* __restrict__ out_s, const int* __restrict__ ws,
                   float* __restrict__ out_m, float* __restrict__ out_l) {
  __shared__ float sred[4];
  int b = blockIdx.x, t = threadIdx.x, lane = t & 63, w = t >> 6;
  int lj = ws[0], mi = ws[1], branch = ws[2], i1 = ws[3], i2 = ws[4], best = ws[5];
  if (b < 1024) {  // m tier, rows r0..r0+3
    int r0 = b * 4;
    bool special = (branch != 4) &&
                   ((i1 >= r0 && i1 < r0 + 4) || (branch == 2 && i2 >= r0 && i2 < r0 + 4));
    if (!special) {
      const f32x4* src = (const f32x4*)(m + (size_t)r0 * DIMV);
      f32x4* dst = (f32x4*)(out_m + (size_t)r0 * DIMV);
#pragma unroll
      for (int k = 0; k < 4; ++k) dst[k * 256 + t] = src[k * 256 + t];
      return;
    }
    for (int rr = 0; rr < 4; ++rr) {
      int row = r0 + rr;
      int mode = 0;
      if ((branch == 0 && row == i1) || (branch == 2 && row == i2)) mode = 1;
      else if (branch == 1 && row == i1) mode = 2;
      else if (branch == 2 && row == i1) mode = 3;
      f32x4* dst = (f32x4*)(out_m + (size_t)row * DIMV);
      if (mode == 0) {
        dst[t] = ((const f32x4*)(m + (size_t)row * DIMV))[t];
      } else if (mode == 1) {
        dst[t] = ((const f32x4*)(out_s + (size_t)best * DIMV))[t];
      } else {
        f32x4 a = ((const f32x4*)(m + (size_t)row * DIMV))[t];
        f32x4 bb = (mode == 2) ? ((const f32x4*)(out_s + (size_t)best * DIMV))[t]
                               : ((const f32x4*)(m + (size_t)i2 * DIMV))[t];
        f32x4 v = (a + bb) * 0.5f;
        float ss = v.x * v.x + v.y * v.y + v.z * v.z + v.w * v.w;
        ss = wave_sum(ss);
        if (lane == 0) sred[w] = ss;
        __syncthreads();
        float nrm = fmaxf(sqrtf(sred[0] + sred[1] + sred[2] + sred[3]), 1e-12f);
        __syncthreads();  // sred reusable by later iterations
        dst[t] = v / nrm;
      }
    }
  } else {  // l tier, rows r0..r0+3
    int r0 = (b - 1024) * 4;
    bool special = (lj >= r0 && lj < r0 + 4);
    if (!special) {
      const f32x4* src = (const f32x4*)(l_memory + (size_t)r0 * DIMV);
      f32x4* dst = (f32x4*)(out_l + (size_t)r0 * DIMV);
#pragma unroll
      for (int k = 0; k < 4; ++k) dst[k * 256 + t] = src[k * 256 + t];
      return;
    }
    for (int rr = 0; rr < 4; ++rr) {
      int row = r0 + rr;
      f32x4 v = ((const f32x4*)(l_memory + (size_t)row * DIMV))[t];
      if (row == lj) {
        // recompute out_m[mi] inline (avoids cross-block dependency on out_m)
        int mode = 0;
        if ((branch == 0 && mi == i1) || (branch == 2 && mi == i2)) mode = 1;
        else if (branch == 1 && mi == i1) mode = 2;
        else if (branch == 2 && mi == i1) mode = 3;
        f32x4 mv;
        if (mode == 0) {
          mv = ((const f32x4*)(m + (size_t)mi * DIMV))[t];
        } else if (mode == 1) {
          mv = ((const f32x4*)(out_s + (size_t)best * DIMV))[t];
        } else {
          f32x4 a = ((const f32x4*)(m + (size_t)mi * DIMV))[t];
          f32x4 bb = (mode == 2) ? ((const f32x4*)(out_s + (size_t)best * DIMV))[t]
                                 : ((const f32x4*)(m + (size_t)i2 * DIMV))[t];
          f32x4 vm = (a + bb) * 0.5f;
          float ss = vm.x * vm.x + vm.y * vm.y + vm.z * vm.z + vm.w * vm.w;
          ss = wave_sum(ss);
          if (lane == 0) sred[w] = ss;
          __syncthreads();
          float nrm = fmaxf(sqrtf(sred[0] + sred[1] + sred[2] + sred[3]), 1e-12f);
          __syncthreads();
          mv = vm / nrm;
        }
        v = v * 0.9f + mv * 0.1f;
      }
      ((f32x4*)(out_l + (size_t)row * DIMV))[t] = v;
    }
  }
}

extern "C" void kernel_launch(void* const* d_in, const int* in_sizes, int n_in,
                              void* d_out, int out_size, void* d_ws, size_t ws_size,
                              hipStream_t stream) {
  const float* cand = (const float*)d_in[0];
  const float* s_memory = (const float*)d_in[1];
  const float* m_memory = (const float*)d_in[2];
  const float* l_memory = (const float*)d_in[3];
  const float* m_utility = (const float*)d_in[4];
  const float* l_utility = (const float*)d_in[5];
  const float* wq = (const float*)d_in[6];
  const float* bq = (const float*)d_in[7];
  const float* wk = (const float*)d_in[8];
  const float* bk = (const float*)d_in[9];
  const int* s_ptr = (const int*)d_in[10];
  (void)bk;  // bk.q is a constant logit shift -> argmax-invariant

  float* out = (float*)d_out;
  float* out_s = out + OUT_S;
  float* out_m = out + OUT_M;
  float* out_l = out + OUT_L;
  float* out_mu = out + OUT_MU;
  float* out_lu = out + OUT_LU;
  float* out_sptr = out + OUT_SPTR;

  float* lsc = out_l;  // scratch region: fully consumed before kI overwrites it
  unsigned short* mb = (unsigned short*)(lsc + SC_BF16);
  float* norms = lsc + SC_NORMS;
  int* topidx = (int*)(lsc + SC_TOPIDX);
  float* lpart = lsc + SC_LPART;
  float* rv = lsc + SC_RV;
  float* lmean = lsc + SC_LMEAN;
  float* logits = lsc + SC_LOGITS;
  int* best = (int*)(lsc + SC_BEST);
  float* cnorm = lsc + SC_BEST + 1;
  float* mnorm = lsc + SC_MNORM;
  float* sims = lsc + SC_SIMS;
  float* pv = lsc + SC_PPV;
  int* pidx = (int*)(lsc + SC_PPI);
  int* wsctl = (int*)d_ws;  // 24 B control block, read by kI after scratch is dead

  kA<<<1408, 256, 0, stream>>>(cand, l_memory, m_memory, norms, lpart, mb, mnorm, rv);
  kT<<<2, 1024, 0, stream>>>(norms, topidx, lpart, lmean);
  kBC<<<640, 256, 0, stream>>>(cand, s_memory, topidx, s_ptr, wq, bq, wk, lmean, out_s, out_sptr,
                               rv);
  kD<<<128, 256, 0, stream>>>(out_s, rv, logits);
  kE<<<1, 256, 0, stream>>>(logits, out_s, best, cnorm);
  kG<<<NPAIR + 1024, 256, 0, stream>>>(mb, mnorm, m_memory, out_s, best, cnorm, pv, pidx, sims);
  kH<<<1, 1024, 0, stream>>>(pv, pidx, sims, m_utility, mnorm, cnorm, best, l_utility,
                             out_mu, out_lu, wsctl);
  kI<<<3072, 256, 0, stream>>>(m_memory, l_memory, out_s, wsctl, out_m, out_l);
}